// Round 7
// baseline (153.783 us; speedup 1.0000x reference)
//
#include <hip/hip_runtime.h>
#include <hip/hip_bf16.h>
#include <hip/hip_cooperative_groups.h>

// CACE message passing. MAX_L=3 -> NL=20, N_RBF=8, RB=8, K=3 -> C=9, NB=5,
// CUTOFF=5.5, T_MP=1, MP_NORM=0.2, N=2000, E=50000. fp32 I/O.
// Round 13: ONE cooperative kernel for the whole pipeline.
//  Wall-time model fit across r0-r12: wall ~= 45us(ws poison fill, fixed) +
//  ~12us * n_dispatches + ~50us real work. Dispatch count is THE lever.
//  k_all phases (grid=N blocks x 192thr, all co-resident, grid.sync between):
//   0: zero counts            (gid stride; weights -> LDS)
//   1: count+rank             (rank kept in REGISTER across syncs; no erank)
//   2: exclusive scan         (block 0 only, N<=2112)
//   3: edge features -> edata (CSR slot; streaming float4 stores)
//   4: nodeA: acc -> Ab(regs) -> Abf2(bf16 packed), Bsh1, chi
//   5: node2: gather chi/Abf2 of senders -> newA -> out
//  A, B0, erank buffers and 5 dispatch boundaries eliminated.
//  Fallback: proven r11 6-dispatch chain (occupancy-checked at launch).

#define CUTF 5.5f
#define MPNORM 0.2f

namespace cg = cooperative_groups;

__constant__ int   d_DEGS[20]  = {0,1,1,1,2,2,2,2,2,2,3,3,3,3,3,3,3,3,3,3};
__constant__ float d_MULTI[20] = {1,1,1,1,1,2,2,1,2,1,1,3,3,3,6,3,1,3,3,1};

// ===================== ONE-SHOT cooperative kernel ==========================
__global__ __launch_bounds__(192, 6) void k_all(
    const float* __restrict__ pos, const float* __restrict__ shifts,
    const float* __restrict__ Wemb, const float* __restrict__ War,
    const int* __restrict__ species, const int* __restrict__ eidx,
    const float* __restrict__ Wrad, const float* __restrict__ Wmem,
    const float* __restrict__ Wchi,
    int* __restrict__ counts, int* __restrict__ offs,
    float* __restrict__ edata, int* __restrict__ esend,
    uint4* __restrict__ Abf2, float* __restrict__ chi,
    float* __restrict__ out, int N, int E) {
  __shared__ float wr_s[288], wm_s[288];   // [deg][r][b], deg stride 72
  __shared__ float wchi_s[40];             // [b][k]
  __shared__ float war_s[64];
  __shared__ float Bsh1[360], Bsh2[360];
  __shared__ int   scanbuf[192];
  cg::grid_group grid = cg::this_grid();
  int t = threadIdx.x, bid = blockIdx.x;
  int gid = bid * 192 + t;
  int gsz = gridDim.x * 192;
  // weights + LDS init (used in phases 4/5; ready long before)
  for (int i = t; i < 256; i += 192) {
    int d = i >> 6, rm = i & 63;
    wr_s[d*72+rm] = Wrad[i];
    wm_s[d*72+rm] = Wmem[i];
  }
  for (int i = t; i < 40; i += 192) wchi_s[i] = Wchi[i];
  if (t < 64) war_s[t] = War[t];
  for (int i = t; i < 360; i += 192) { Bsh1[i] = 0.0f; Bsh2[i] = 0.0f; }
  // ---- phase 0: zero counts ----
  for (int i = gid; i < N; i += gsz) counts[i] = 0;
  grid.sync();
  // ---- phase 1: count + rank (rank stays in register) ----
  int es = 0, er = 0, rk = 0;
  bool has_e = (gid < E);
  if (has_e) {
    es = eidx[gid];
    er = eidx[E + gid];
    rk = atomicAdd(&counts[er], 1);
  }
  grid.sync();
  // ---- phase 2: exclusive scan on block 0 (N <= 2112) ----
  if (bid == 0) {
    int loc[11]; int sum = 0;
    #pragma unroll
    for (int i = 0; i < 11; i++) {
      int idx = t*11 + i;
      int v = (idx < N) ? counts[idx] : 0;
      loc[i] = sum; sum += v;
    }
    scanbuf[t] = sum; __syncthreads();
    for (int d = 1; d < 192; d <<= 1) {
      int add = (t >= d) ? scanbuf[t-d] : 0;
      __syncthreads();
      scanbuf[t] += add;
      __syncthreads();
    }
    int excl = scanbuf[t] - sum;
    #pragma unroll
    for (int i = 0; i < 11; i++) {
      int idx = t*11 + i;
      if (idx < N) offs[idx] = excl + loc[i];
    }
    if (t == 191) offs[N] = scanbuf[191];
    __threadfence();
  }
  grid.sync();
  // ---- phase 3: per-edge features -> CSR slot (streaming stores) ----
  if (has_e) {
    int dst = offs[er] + rk;
    float4* eb4 = reinterpret_cast<float4*>(edata + (size_t)dst * 48);
    float vx = pos[er*3+0] - pos[es*3+0] + shifts[gid*3+0];
    float vy = pos[er*3+1] - pos[es*3+1] + shifts[gid*3+1];
    float vz = pos[er*3+2] - pos[es*3+2] + shifts[gid*3+2];
    float len = sqrtf(vx*vx + vy*vy + vz*vz);
    float inv = 1.0f / (len + 1e-9f);
    float ux = vx*inv, uy = vy*inv, uz = vz*inv;
    float uu = len * (1.0f/CUTF);
    float u2 = uu*uu, u6 = u2*u2*u2;
    float fcut = (uu < 1.0f) ? (1.0f - 28.0f*u6 + 48.0f*u6*uu - 21.0f*u6*u2) : 0.0f;
    float x = 3.14159265358979f * uu;
    float sn = sinf(x), c2 = 2.0f*cosf(x), snm1 = 0.0f;
    float pref = sqrtf(2.0f/CUTF) / (len + 1e-20f);
    float rad[8];
    #pragma unroll
    for (int k = 0; k < 8; k++) {
      rad[k] = pref * sn;
      float nxt = c2*sn - snm1; snm1 = sn; sn = nxt;
    }
    eb4[0] = make_float4(rad[0]*fcut, rad[1]*fcut, rad[2]*fcut, rad[3]*fcut);
    eb4[1] = make_float4(rad[4]*fcut, rad[5]*fcut, rad[6]*fcut, rad[7]*fcut);
    float fr[8];
    #pragma unroll
    for (int b = 0; b < 8; b++) {
      float a = 0.0f;
      #pragma unroll
      for (int k = 0; k < 8; k++) a += rad[k] * war_s[k*8+b];
      fr[b] = a * fcut;
    }
    eb4[2] = make_float4(fr[0], fr[1], fr[2], fr[3]);
    eb4[3] = make_float4(fr[4], fr[5], fr[6], fr[7]);
    float px2 = ux*ux, py2 = uy*uy, pz2 = uz*uz;
    eb4[4] = make_float4(1.0f, ux, uy, uz);
    eb4[5] = make_float4(px2, ux*uy, ux*uz, py2);
    eb4[6] = make_float4(uy*uz, pz2, px2*ux, px2*uy);
    eb4[7] = make_float4(px2*uz, ux*py2, ux*uy*uz, ux*pz2);
    eb4[8] = make_float4(py2*uy, py2*uz, uy*pz2, pz2*uz);
    int zs = species[es], zr = species[er];
    float es0 = Wemb[zs*3+0], es1 = Wemb[zs*3+1], es2 = Wemb[zs*3+2];
    float er0 = Wemb[zr*3+0], er1 = Wemb[zr*3+1], er2 = Wemb[zr*3+2];
    eb4[9]  = make_float4(es0*er0, es0*er1, es0*er2, es1*er0);
    eb4[10] = make_float4(es1*er1, es1*er2, es2*er0, es2*er1);
    eb4[11] = make_float4(es2*er2, 0.0f, 0.0f, 0.0f);
    esend[dst] = es;
  }
  __threadfence();
  grid.sync();
  // ---- phase 4: nodeA (n = bid): acc -> Ab(regs) -> Abf2, Bsh1, chi ----
  int n = bid;
  int l = t / 9, c = t - l*9;
  bool act = t < 180;
  int ll = act ? l : 0, cc = act ? c : 0;
  int tt = act ? t : 0;
  int deg = d_DEGS[ll];
  float mlt = d_MULTI[ll];
  int kk = 1 + deg;
  int start = offs[n], end = offs[n+1];
  float acc[8];
  #pragma unroll
  for (int r = 0; r < 8; r++) acc[r] = 0.0f;
  #pragma unroll 4
  for (int j = start; j < end; j++) {
    const float* row = edata + (size_t)j * 48;       // SEQUENTIAL
    float p = row[16+ll] * row[36+cc];
    #pragma unroll
    for (int r = 0; r < 8; r++) acc[r] += row[r] * p;
  }
  const float* wp = &wr_s[deg*72];
  float Ab[8];                                       // lives across grid.sync
  #pragma unroll
  for (int b = 0; b < 8; b++) {
    float a = 0.0f;
    #pragma unroll
    for (int r = 0; r < 8; r++) a += acc[r] * wp[r*8+b];
    Ab[b] = a;
  }
  if (act) {
    unsigned int pk[4];
    #pragma unroll
    for (int bp = 0; bp < 4; bp++) {
      __hip_bfloat16 blo = __float2bfloat16(Ab[2*bp]);
      __hip_bfloat16 bhi = __float2bfloat16(Ab[2*bp+1]);
      pk[bp] = (unsigned int)(*reinterpret_cast<unsigned short*>(&blo))
             | ((unsigned int)(*reinterpret_cast<unsigned short*>(&bhi)) << 16);
    }
    uint4 qv; qv.x = pk[0]; qv.y = pk[1]; qv.z = pk[2]; qv.w = pk[3];
    Abf2[(size_t)n*180 + t] = qv;                    // one 16B store/lane
    if (l == 0) {
      #pragma unroll
      for (int b = 0; b < 8; b++) Bsh1[b*45 + c] = Ab[b];
    }
    #pragma unroll
    for (int b = 0; b < 8; b++) atomicAdd(&Bsh1[b*45 + kk*9 + c], mlt*Ab[b]*Ab[b]);
  }
  __syncthreads();
  if (t < 9) {
    float s = 0.0f;
    for (int b = 0; b < 8; b++)
      #pragma unroll
      for (int kq = 0; kq < 5; kq++) s += Bsh1[b*45 + kq*9 + t] * wchi_s[b*5 + kq];
    chi[n*9 + t] = s;
  }
  __threadfence();
  grid.sync();
  // ---- phase 5: node2: gather chi/Abf2 of senders -> newA -> out ----
  float Sacc[8], Racc[8];
  #pragma unroll
  for (int r = 0; r < 8; r++) { Sacc[r] = 0.0f; Racc[r] = 0.0f; }
  #pragma unroll 2
  for (int j = start; j < end; j++) {
    const float* row = edata + (size_t)j * 48;       // SEQUENTIAL
    int snd = esend[j];                              // SEQUENTIAL
    float ch = chi[snd*9 + cc];                      // depth-1 gather
    const uint4 qv = Abf2[(size_t)snd*180 + tt];     // depth-1, ONE 16B load
    float pch = row[16+ll] * row[36+cc] * ch;
    #pragma unroll
    for (int r = 0; r < 8; r++) Sacc[r] += row[r] * pch;
    float a0 = __uint_as_float(qv.x << 16), a1 = __uint_as_float(qv.x & 0xffff0000u);
    float a2 = __uint_as_float(qv.y << 16), a3 = __uint_as_float(qv.y & 0xffff0000u);
    float a4 = __uint_as_float(qv.z << 16), a5 = __uint_as_float(qv.z & 0xffff0000u);
    float a6 = __uint_as_float(qv.w << 16), a7 = __uint_as_float(qv.w & 0xffff0000u);
    Racc[0] += a0*row[8];  Racc[1] += a1*row[9];
    Racc[2] += a2*row[10]; Racc[3] += a3*row[11];
    Racc[4] += a4*row[12]; Racc[5] += a5*row[13];
    Racc[6] += a6*row[14]; Racc[7] += a7*row[15];
  }
  if (act) {
    const float* wrp = &wr_s[deg*72];
    const float* wmp = &wm_s[deg*72];
    float newA[8];
    #pragma unroll
    for (int b = 0; b < 8; b++) {
      float mem = 0.0f, ab = 0.0f;
      #pragma unroll
      for (int r = 0; r < 8; r++) { mem += Ab[r]*wmp[r*8+b]; ab += Sacc[r]*wrp[r*8+b]; }
      newA[b] = (Racc[b] + ab)*MPNORM + mem;
    }
    if (l == 0) {
      #pragma unroll
      for (int b = 0; b < 8; b++) Bsh2[b*45 + c] = newA[b];
    }
    #pragma unroll
    for (int b = 0; b < 8; b++) atomicAdd(&Bsh2[b*45 + kk*9 + c], mlt*newA[b]*newA[b]);
  }
  __syncthreads();
  float2* out2 = reinterpret_cast<float2*>(out);
  for (int i = t; i < 360; i += 192) {
    float2 pk2; pk2.x = Bsh1[i]; pk2.y = Bsh2[i];
    out2[(size_t)n*360 + i] = pk2;                   // coalesced 8B stores
  }
}

// ==================== fallback path (proven r11 chain) ======================
__global__ void k_count(const int* __restrict__ eidx, int* __restrict__ counts,
                        int* __restrict__ erank, int E) {
  int e = blockIdx.x * blockDim.x + threadIdx.x;
  if (e < E) erank[e] = atomicAdd(&counts[eidx[E + e]], 1);
}

__global__ void k_scan(const int* __restrict__ counts, int* __restrict__ offs, int N) {
  __shared__ int part[256];
  int t = threadIdx.x;
  int local[8]; int sum = 0;
  #pragma unroll
  for (int i = 0; i < 8; i++) {
    int idx = t*8 + i;
    int v = (idx < N) ? counts[idx] : 0;
    local[i] = sum; sum += v;
  }
  part[t] = sum; __syncthreads();
  for (int d = 1; d < 256; d <<= 1) {
    int add = (t >= d) ? part[t-d] : 0;
    __syncthreads();
    part[t] += add;
    __syncthreads();
  }
  int excl = part[t] - sum;
  #pragma unroll
  for (int i = 0; i < 8; i++) {
    int idx = t*8 + i;
    if (idx < N) offs[idx] = excl + local[i];
  }
  if (t == 255) offs[N] = part[255];
}

__global__ __launch_bounds__(64) void k_edge(
                       const float* __restrict__ pos,
                       const float* __restrict__ shifts,
                       const float* __restrict__ Wemb,
                       const float* __restrict__ War,
                       const int* __restrict__ species,
                       const int* __restrict__ eidx,
                       const int* __restrict__ offs,
                       const int* __restrict__ erank,
                       float* __restrict__ edata,
                       int* __restrict__ esend,
                       int E) {
  __shared__ float war_s[64];
  int t = threadIdx.x;
  war_s[t] = War[t];
  __syncthreads();
  int e = blockIdx.x * 64 + t;
  if (e >= E) return;
  int s  = eidx[e];
  int rI = eidx[E + e];
  int rk = erank[e];
  float vx = pos[rI*3+0] - pos[s*3+0] + shifts[e*3+0];
  float vy = pos[rI*3+1] - pos[s*3+1] + shifts[e*3+1];
  float vz = pos[rI*3+2] - pos[s*3+2] + shifts[e*3+2];
  float len = sqrtf(vx*vx + vy*vy + vz*vz);
  float inv = 1.0f / (len + 1e-9f);
  float ux = vx*inv, uy = vy*inv, uz = vz*inv;
  float uu = len * (1.0f/CUTF);
  float u2 = uu*uu, u6 = u2*u2*u2;
  float fcut = (uu < 1.0f) ? (1.0f - 28.0f*u6 + 48.0f*u6*uu - 21.0f*u6*u2) : 0.0f;
  float x = 3.14159265358979f * uu;
  float sn = sinf(x), c2 = 2.0f*cosf(x), snm1 = 0.0f;
  float pref = sqrtf(2.0f/CUTF) / (len + 1e-20f);
  float rad[8];
  float v[48];
  #pragma unroll
  for (int k = 0; k < 8; k++) {
    rad[k] = pref * sn;
    v[k]   = rad[k] * fcut;
    float nxt = c2*sn - snm1; snm1 = sn; sn = nxt;
  }
  #pragma unroll
  for (int b = 0; b < 8; b++) {
    float a = 0.0f;
    #pragma unroll
    for (int k = 0; k < 8; k++) a += rad[k] * war_s[k*8+b];
    v[8+b] = a * fcut;
  }
  float px2 = ux*ux, py2 = uy*uy, pz2 = uz*uz;
  v[16] = 1.0f; v[17] = ux;     v[18] = uy;     v[19] = uz;
  v[20] = px2;  v[21] = ux*uy;  v[22] = ux*uz;  v[23] = py2;
  v[24] = uy*uz;v[25] = pz2;
  v[26] = px2*ux; v[27] = px2*uy; v[28] = px2*uz; v[29] = ux*py2;
  v[30] = ux*uy*uz; v[31] = ux*pz2; v[32] = py2*uy; v[33] = py2*uz;
  v[34] = uy*pz2; v[35] = pz2*uz;
  int zs = species[s], zr = species[rI];
  float es0 = Wemb[zs*3+0], es1 = Wemb[zs*3+1], es2 = Wemb[zs*3+2];
  float er0 = Wemb[zr*3+0], er1 = Wemb[zr*3+1], er2 = Wemb[zr*3+2];
  v[36] = es0*er0; v[37] = es0*er1; v[38] = es0*er2;
  v[39] = es1*er0; v[40] = es1*er1; v[41] = es1*er2;
  v[42] = es2*er0; v[43] = es2*er1; v[44] = es2*er2;
  v[45] = 0.0f; v[46] = 0.0f; v[47] = 0.0f;
  int dst = offs[rI] + rk;
  float4* eb4 = reinterpret_cast<float4*>(edata + (size_t)dst * 48);
  #pragma unroll
  for (int w = 0; w < 12; w++)
    eb4[w] = make_float4(v[4*w], v[4*w+1], v[4*w+2], v[4*w+3]);
  esend[dst] = s;
}

__global__ __launch_bounds__(192) void k_nodeA(
    const float* __restrict__ edata, const int* __restrict__ offs,
    const float* __restrict__ Wrad, const float* __restrict__ Wchi,
    float* __restrict__ A, uint4* __restrict__ Abf2,
    float* __restrict__ chi, float* __restrict__ B0, int N) {
  __shared__ float wr_s[288];
  __shared__ float wchi_s[40];
  __shared__ float Bsh[360];
  int t = threadIdx.x, n = blockIdx.x;
  for (int i = t; i < 256; i += 192) { int d = i >> 6, rm = i & 63; wr_s[d*72+rm] = Wrad[i]; }
  for (int i = t; i < 40;  i += 192) wchi_s[i] = Wchi[i];
  for (int i = t; i < 360; i += 192) Bsh[i] = 0.0f;
  int l = t / 9, c = t - l*9;
  bool act = t < 180;
  int ll = act ? l : 0, cc = act ? c : 0;
  float acc[8];
  #pragma unroll
  for (int r = 0; r < 8; r++) acc[r] = 0.0f;
  int start = offs[n], end = offs[n+1];
  #pragma unroll 4
  for (int j = start; j < end; j++) {
    const float* row = edata + (size_t)j * 48;
    float p = row[16+ll] * row[36+cc];
    #pragma unroll
    for (int r = 0; r < 8; r++) acc[r] += row[r] * p;
  }
  __syncthreads();
  int deg = act ? d_DEGS[ll] : 0;
  const float* wp = &wr_s[deg*72];
  float Ab[8];
  #pragma unroll
  for (int b = 0; b < 8; b++) {
    float a = 0.0f;
    #pragma unroll
    for (int r = 0; r < 8; r++) a += acc[r] * wp[r*8+b];
    Ab[b] = a;
  }
  if (act) {
    #pragma unroll
    for (int b = 0; b < 8; b++) A[(size_t)n*1440 + t*8 + b] = Ab[b];
    unsigned int pk[4];
    #pragma unroll
    for (int bp = 0; bp < 4; bp++) {
      __hip_bfloat16 blo = __float2bfloat16(Ab[2*bp]);
      __hip_bfloat16 bhi = __float2bfloat16(Ab[2*bp+1]);
      pk[bp] = (unsigned int)(*reinterpret_cast<unsigned short*>(&blo))
             | ((unsigned int)(*reinterpret_cast<unsigned short*>(&bhi)) << 16);
    }
    uint4 qv; qv.x = pk[0]; qv.y = pk[1]; qv.z = pk[2]; qv.w = pk[3];
    Abf2[(size_t)n*180 + t] = qv;
    if (l == 0) {
      #pragma unroll
      for (int b = 0; b < 8; b++) Bsh[b*45 + c] = Ab[b];
    }
    float mlt = d_MULTI[ll]; int kk = 1 + deg;
    #pragma unroll
    for (int b = 0; b < 8; b++) atomicAdd(&Bsh[b*45 + kk*9 + c], mlt*Ab[b]*Ab[b]);
  }
  __syncthreads();
  if (t < 9) {
    float s = 0.0f;
    for (int b = 0; b < 8; b++)
      #pragma unroll
      for (int kq = 0; kq < 5; kq++) s += Bsh[b*45 + kq*9 + t] * wchi_s[b*5 + kq];
    chi[n*9 + t] = s;
  }
  for (int i = t; i < 360; i += 192)
    B0[(size_t)n*360 + i] = Bsh[i];
}

__global__ __launch_bounds__(192) void k_node2(
    const float* __restrict__ edata, const int* __restrict__ esend,
    const int* __restrict__ offs,
    const float* __restrict__ Wrad, const float* __restrict__ Wmem,
    const float* __restrict__ A, const uint4* __restrict__ Abf2,
    const float* __restrict__ chi, const float* __restrict__ B0,
    float* __restrict__ out, int N) {
  __shared__ float wr_s[288], wm_s[288];
  __shared__ float Bsh[360];
  int t = threadIdx.x, n = blockIdx.x;
  for (int i = t; i < 256; i += 192) {
    int d = i >> 6, rm = i & 63;
    wr_s[d*72+rm] = Wrad[i];
    wm_s[d*72+rm] = Wmem[i];
  }
  for (int i = t; i < 360; i += 192) Bsh[i] = 0.0f;
  int l = t / 9, c = t - l*9;
  bool act = t < 180;
  int ll = act ? l : 0, cc = act ? c : 0;
  int tt = act ? t : 0;
  float Sacc[8], ARacc[8];
  #pragma unroll
  for (int r = 0; r < 8; r++) { Sacc[r] = 0.0f; ARacc[r] = 0.0f; }
  int start = offs[n], end = offs[n+1];
  #pragma unroll 4
  for (int j = start; j < end; j++) {
    const float* row = edata + (size_t)j * 48;
    int snd = esend[j];
    float ch = chi[snd*9 + cc];
    float pch = row[16+ll] * row[36+cc] * ch;
    #pragma unroll
    for (int r = 0; r < 8; r++) Sacc[r] += row[r] * pch;
    const uint4 qv = Abf2[(size_t)snd*180 + tt];
    float a0 = __uint_as_float(qv.x << 16), a1 = __uint_as_float(qv.x & 0xffff0000u);
    float a2 = __uint_as_float(qv.y << 16), a3 = __uint_as_float(qv.y & 0xffff0000u);
    float a4 = __uint_as_float(qv.z << 16), a5 = __uint_as_float(qv.z & 0xffff0000u);
    float a6 = __uint_as_float(qv.w << 16), a7 = __uint_as_float(qv.w & 0xffff0000u);
    ARacc[0] += a0*row[8];  ARacc[1] += a1*row[9];
    ARacc[2] += a2*row[10]; ARacc[3] += a3*row[11];
    ARacc[4] += a4*row[12]; ARacc[5] += a5*row[13];
    ARacc[6] += a6*row[14]; ARacc[7] += a7*row[15];
  }
  __syncthreads();
  if (act) {
    int deg = d_DEGS[ll];
    const float* wrp = &wr_s[deg*72];
    const float* wmp = &wm_s[deg*72];
    const float* aop = A + (size_t)n*1440 + t*8;
    float aown[8];
    #pragma unroll
    for (int r = 0; r < 8; r++) aown[r] = aop[r];
    float newA[8];
    #pragma unroll
    for (int b = 0; b < 8; b++) {
      float mem = 0.0f, ab = 0.0f;
      #pragma unroll
      for (int r = 0; r < 8; r++) { mem += aown[r]*wmp[r*8+b]; ab += Sacc[r]*wrp[r*8+b]; }
      newA[b] = (ARacc[b] + ab)*MPNORM + mem;
    }
    if (l == 0) {
      #pragma unroll
      for (int b = 0; b < 8; b++) Bsh[b*45 + c] = newA[b];
    }
    float mlt = d_MULTI[ll]; int kk = 1 + deg;
    #pragma unroll
    for (int b = 0; b < 8; b++) atomicAdd(&Bsh[b*45 + kk*9 + c], mlt*newA[b]*newA[b]);
  }
  __syncthreads();
  float2* out2 = reinterpret_cast<float2*>(out);
  for (int i = t; i < 360; i += 192) {
    float2 pk; pk.x = B0[(size_t)n*360 + i]; pk.y = Bsh[i];
    out2[(size_t)n*360 + i] = pk;
  }
}

extern "C" void kernel_launch(void* const* d_in, const int* in_sizes, int n_in,
                              void* d_out, int out_size, void* d_ws, size_t ws_size,
                              hipStream_t stream) {
  const float* pos    = (const float*)d_in[0];
  const float* shifts = (const float*)d_in[1];
  const float* Wemb   = (const float*)d_in[2];
  const float* Wrad   = (const float*)d_in[3];
  const float* Wmem   = (const float*)d_in[4];
  const float* War    = (const float*)d_in[5];
  const float* Wchi   = (const float*)d_in[6];
  const int* species = (const int*)d_in[7];
  const int* eidx    = (const int*)d_in[8];
  float* out = (float*)d_out;
  int N = in_sizes[7];
  int E = in_sizes[8] / 2;

  char* base = (char*)d_ws;
  size_t off = 0;
  float* edata = (float*)(base + off); off += (size_t)E*48*4;          // 9.6 MB
  float* A     = (float*)(base + off); off += (size_t)N*1440*4;        // fallback only
  uint4* Abf2  = (uint4*)(base + off); off += (size_t)N*180*16;        // 5.76 MB
  float* chi   = (float*)(base + off); off += (size_t)N*9*4;
  float* B0    = (float*)(base + off); off += (size_t)N*360*4;         // fallback only
  int* counts  = (int*)(base + off);   off += (size_t)N*4;
  int* offs    = (int*)(base + off);   off += (((size_t)(N+1)*4) + 15) & ~(size_t)15;
  int* esend   = (int*)(base + off);   off += (size_t)E*4;
  int* erank   = (int*)(base + off);   off += (((size_t)E*4) + 15) & ~(size_t)15;  // fallback only

  // One-time capability check for the single-kernel coop path (pure queries,
  // graph-capture safe; coop launch pattern verified working in r8/r12).
  static int s_coop = -1;
  static int s_N = 0, s_E = 0;
  if (s_coop < 0 || s_N != N || s_E != E) {
    int dev = 0; hipGetDevice(&dev);
    int nCU = 0;
    hipDeviceGetAttribute(&nCU, hipDeviceAttributeMultiprocessorCount, dev);
    int maxB = 0;
    hipError_t oe = hipOccupancyMaxActiveBlocksPerMultiprocessor(
        &maxB, reinterpret_cast<const void*>(k_all), 192, 0);
    s_coop = (oe == hipSuccess && nCU > 0 &&
              (long)maxB * nCU >= N &&          // all blocks co-resident
              (long)N * 192 >= E &&             // 1 edge/thread coverage
              N <= 2112) ? 1 : 0;               // scan capacity (192*11)
    s_N = N; s_E = E;
  }

  bool done = false;
  if (s_coop == 1) {
    void* args[] = {(void*)&pos, (void*)&shifts, (void*)&Wemb, (void*)&War,
                    (void*)&species, (void*)&eidx,
                    (void*)&Wrad, (void*)&Wmem, (void*)&Wchi,
                    (void*)&counts, (void*)&offs,
                    (void*)&edata, (void*)&esend,
                    (void*)&Abf2, (void*)&chi, (void*)&out,
                    (void*)&N, (void*)&E};
    hipError_t le = hipLaunchCooperativeKernel(
        reinterpret_cast<void*>(k_all), dim3(N), dim3(192), args, 0, stream);
    if (le == hipSuccess) done = true; else s_coop = 0;
  }
  if (!done) {
    hipMemsetAsync(counts, 0, (size_t)N*4, stream);
    k_count<<<(E + 255) / 256, 256, 0, stream>>>(eidx, counts, erank, E);
    k_scan<<<1, 256, 0, stream>>>(counts, offs, N);
    k_edge<<<(E + 63) / 64, 64, 0, stream>>>(pos, shifts, Wemb, War, species, eidx,
                                             offs, erank, edata, esend, E);
    k_nodeA<<<N, 192, 0, stream>>>(edata, offs, Wrad, Wchi, A, Abf2, chi, B0, N);
    k_node2<<<N, 192, 0, stream>>>(edata, esend, offs, Wrad, Wmem, A, Abf2, chi, B0, out, N);
  }
}